// Round 1
// baseline (383.165 us; speedup 1.0000x reference)
//
#include <hip/hip_runtime.h>

// Problem constants (fixed by the reference setup_inputs):
// feat  [N=16, C=256, H=128, W=128] fp32
// logit [N=16, CLS=9, H=128, W=128] fp32
// out   [N, C, CLS] fp32 (broadcast of [C, CLS] protos)
#define HWN   16384            // H*W
#define NB    16               // batch
#define CH    256              // channels
#define CLS   9                // classes
#define PTOT  (NB * HWN)       // total pixels

// ---------------------------------------------------------------------------
// Kernel 1: per-pixel argmax over CLS logits -> uint8 label; per-class counts.
// ---------------------------------------------------------------------------
__global__ __launch_bounds__(256) void label_kernel(
    const float* __restrict__ logit,
    unsigned char* __restrict__ labels,
    int* __restrict__ counts)
{
    __shared__ int hist[CLS];
    if (threadIdx.x < CLS) hist[threadIdx.x] = 0;
    __syncthreads();

    const int p  = blockIdx.x * 256 + threadIdx.x;   // grid = PTOT/256 exactly
    const int n  = p / HWN;
    const int hw = p - n * HWN;
    const float* base = logit + (size_t)n * CLS * HWN + hw;

    float best = base[0];
    int   bi   = 0;
#pragma unroll
    for (int k = 1; k < CLS; ++k) {
        float v = base[(size_t)k * HWN];
        if (v > best) { best = v; bi = k; }   // strict > == first-max (argmax semantics)
    }
    labels[p] = (unsigned char)bi;
    atomicAdd(&hist[bi], 1);
    __syncthreads();
    if (threadIdx.x < CLS) atomicAdd(&counts[threadIdx.x], hist[threadIdx.x]);
}

// ---------------------------------------------------------------------------
// Kernel 2: per-(n,c) slab: sum feat into per-class bins. One block per (n,c).
// float4 feat loads (coalesced, 16 B/lane), uchar4 label loads (L2-resident).
// ---------------------------------------------------------------------------
__global__ __launch_bounds__(256) void sum_kernel(
    const float* __restrict__ feat,
    const unsigned char* __restrict__ labels,
    float* __restrict__ sums)   // [CLS][CH]
{
    const int b = blockIdx.x;        // b = n*CH + c
    const int n = b >> 8;            // / CH
    const int c = b & (CH - 1);

    const float4*       f4 = (const float4*)(feat + (size_t)b * HWN);
    const unsigned int* l4 = (const unsigned int*)(labels + (size_t)n * HWN);

    float s[CLS];
#pragma unroll
    for (int k = 0; k < CLS; ++k) s[k] = 0.0f;

    // HWN/4 = 4096 float4 chunks, 256 threads -> 16 iterations each.
    for (int i = threadIdx.x; i < HWN / 4; i += 256) {
        const float4       v  = f4[i];
        const unsigned int lu = l4[i];
#pragma unroll
        for (int j = 0; j < 4; ++j) {
            const float x = (j == 0) ? v.x : (j == 1) ? v.y : (j == 2) ? v.z : v.w;
            const int   l = (lu >> (8 * j)) & 255;
#pragma unroll
            for (int k = 0; k < CLS; ++k)
                s[k] += (l == k) ? x : 0.0f;
        }
    }

    // Wave(64) shuffle-tree reduction per class.
#pragma unroll
    for (int k = 0; k < CLS; ++k)
        for (int off = 32; off > 0; off >>= 1)
            s[k] += __shfl_down(s[k], off, 64);

    __shared__ float wsum[4][CLS];
    const int wave = threadIdx.x >> 6;
    const int lane = threadIdx.x & 63;
    if (lane == 0) {
#pragma unroll
        for (int k = 0; k < CLS; ++k) wsum[wave][k] = s[k];
    }
    __syncthreads();

    if (threadIdx.x < CLS) {
        const int k = threadIdx.x;
        const float t = wsum[0][k] + wsum[1][k] + wsum[2][k] + wsum[3][k];
        atomicAdd(&sums[k * CH + c], t);   // 16 adds per (k,c) across the grid
    }
}

// ---------------------------------------------------------------------------
// Kernel 3: out[n][c][k] = sums[k][c] / max(count[k],1), broadcast over n.
// ---------------------------------------------------------------------------
__global__ __launch_bounds__(256) void finalize_kernel(
    const float* __restrict__ sums,
    const int* __restrict__ counts,
    float* __restrict__ out)
{
    const int idx = blockIdx.x * 256 + threadIdx.x;  // grid covers NB*CH*CLS exactly
    if (idx >= NB * CH * CLS) return;
    const int k = idx % CLS;
    const int c = (idx / CLS) % CH;
    const float cnt = (float)max(counts[k], 1);
    out[idx] = sums[k * CH + c] / cnt;
}

// ---------------------------------------------------------------------------
extern "C" void kernel_launch(void* const* d_in, const int* in_sizes, int n_in,
                              void* d_out, int out_size, void* d_ws, size_t ws_size,
                              hipStream_t stream)
{
    const float* feat  = (const float*)d_in[0];
    const float* logit = (const float*)d_in[1];
    // d_in[2] is cls_num (== 9, fixed by the problem); hardcoded as CLS.

    // Workspace layout (ws is re-poisoned 0xAA before every timed call):
    //   [0, 36864)         float sums[CLS][CH]
    //   [36864, 36928)     int counts[CLS] (padded to 64 B)
    //   [36928, 299072)    uint8 labels[PTOT]
    char* ws = (char*)d_ws;
    float*         sums   = (float*)ws;
    int*           counts = (int*)(ws + CLS * CH * sizeof(float));
    unsigned char* labels = (unsigned char*)(ws + CLS * CH * sizeof(float) + 64);

    hipMemsetAsync(d_ws, 0, CLS * CH * sizeof(float) + 64, stream);

    label_kernel<<<PTOT / 256, 256, 0, stream>>>(logit, labels, counts);
    sum_kernel<<<NB * CH, 256, 0, stream>>>(feat, labels, sums);
    finalize_kernel<<<(NB * CH * CLS + 255) / 256, 256, 0, stream>>>(sums, counts, (float*)d_out);
}

// Round 2
// 374.289 us; speedup vs baseline: 1.0237x; 1.0237x over previous
//
#include <hip/hip_runtime.h>

// Problem constants (fixed by the reference setup_inputs):
// feat  [N=16, C=256, H=128, W=128] fp32
// logit [N=16, CLS=9, H=128, W=128] fp32
// out   [N, C, CLS] fp32 (broadcast of [C, CLS] protos)
#define HWN   16384            // H*W
#define NB    16               // batch
#define CH    256              // channels
#define CLS   9                // classes
#define PTOT  (NB * HWN)       // 262144 pixels
#define LBLK  (PTOT / 1024)    // 256 label blocks (4 px/thread, 256 thr)
#define SBLK  (NB * CH)        // 4096 sum blocks

// ---------------------------------------------------------------------------
// K1: per-pixel argmax over CLS logits. 4 pixels/thread -> float4 logit loads,
// packed uint label store. Per-block histogram written to a DISTINCT slot
// (no global atomics, no zero-init needed: every word fully overwritten).
// ---------------------------------------------------------------------------
__global__ __launch_bounds__(256) void label_kernel(
    const float* __restrict__ logit,
    unsigned int* __restrict__ labels4,   // [PTOT/4] packed 4 labels/uint
    int* __restrict__ hist)               // [LBLK][CLS]
{
    __shared__ int h[CLS];
    if (threadIdx.x < CLS) h[threadIdx.x] = 0;
    __syncthreads();

    const int t  = blockIdx.x * 256 + threadIdx.x;  // packed-uint index
    const int p0 = t << 2;                          // first pixel of the 4
    const int n  = p0 >> 14;                        // / HWN (same n for all 4)
    const int hw = p0 & (HWN - 1);
    const float* base = logit + (size_t)n * CLS * HWN + hw;

    float4 best = *(const float4*)base;             // hw % 4 == 0 -> aligned
    int b0 = 0, b1 = 0, b2 = 0, b3 = 0;
#pragma unroll
    for (int k = 1; k < CLS; ++k) {
        const float4 v = *(const float4*)(base + (size_t)k * HWN);
        if (v.x > best.x) { best.x = v.x; b0 = k; }  // strict > == jnp.argmax tie-break
        if (v.y > best.y) { best.y = v.y; b1 = k; }
        if (v.z > best.z) { best.z = v.z; b2 = k; }
        if (v.w > best.w) { best.w = v.w; b3 = k; }
    }
    labels4[t] = (unsigned)b0 | ((unsigned)b1 << 8) |
                 ((unsigned)b2 << 16) | ((unsigned)b3 << 24);

    atomicAdd(&h[b0], 1); atomicAdd(&h[b1], 1);
    atomicAdd(&h[b2], 1); atomicAdd(&h[b3], 1);
    __syncthreads();
    if (threadIdx.x < CLS) hist[blockIdx.x * CLS + threadIdx.x] = h[threadIdx.x];
}

// ---------------------------------------------------------------------------
// K2: one block per (n,c) slab of 16384 contiguous floats. float4 feat loads,
// uint label loads (L2-resident). Register class-bins -> wave shuffle tree ->
// cross-wave LDS -> per-block partial written to a DISTINCT slot (no atomics).
// ---------------------------------------------------------------------------
__global__ __launch_bounds__(256) void sum_kernel(
    const float* __restrict__ feat,
    const unsigned int* __restrict__ labels4,
    float* __restrict__ partial)   // [SBLK][CLS]
{
    const int b = blockIdx.x;            // b = n*CH + c == feat slab index
    const int n = b >> 8;

    const float4*       f4 = (const float4*)(feat + (size_t)b * HWN);
    const unsigned int* l4 = labels4 + (size_t)n * (HWN / 4);

    float s[CLS];
#pragma unroll
    for (int k = 0; k < CLS; ++k) s[k] = 0.0f;

    // 4096 float4 chunks, 256 threads -> 16 iterations each.
#pragma unroll 4
    for (int i = threadIdx.x; i < HWN / 4; i += 256) {
        const float4       v  = f4[i];
        const unsigned int lu = l4[i];
#pragma unroll
        for (int j = 0; j < 4; ++j) {
            const float x = (j == 0) ? v.x : (j == 1) ? v.y : (j == 2) ? v.z : v.w;
            const int   l = (lu >> (8 * j)) & 255;
#pragma unroll
            for (int k = 0; k < CLS; ++k)
                s[k] += (l == k) ? x : 0.0f;
        }
    }

    // Wave(64) shuffle-tree reduction per class, then cross-wave via LDS.
#pragma unroll
    for (int k = 0; k < CLS; ++k)
        for (int off = 32; off > 0; off >>= 1)
            s[k] += __shfl_down(s[k], off, 64);

    __shared__ float wsum[4][CLS];
    const int wave = threadIdx.x >> 6;
    if ((threadIdx.x & 63) == 0) {
#pragma unroll
        for (int k = 0; k < CLS; ++k) wsum[wave][k] = s[k];
    }
    __syncthreads();

    if (threadIdx.x < CLS) {
        const int k = threadIdx.x;
        partial[b * CLS + k] = wsum[0][k] + wsum[1][k] + wsum[2][k] + wsum[3][k];
    }
}

// ---------------------------------------------------------------------------
// K3: reduce 16 n-partials per (c,k), divide by counts (reduced from hist),
// broadcast-write out[n][c][k]. 9 blocks x 256 threads = 2304 = CH*CLS.
// ---------------------------------------------------------------------------
__global__ __launch_bounds__(256) void finalize_kernel(
    const float* __restrict__ partial,  // [SBLK][CLS]
    const int* __restrict__ hist,       // [LBLK][CLS]
    float* __restrict__ out)            // [NB][CH][CLS]
{
    // --- counts: tree-reduce the 256 per-block histograms (redundant/block) ---
    __shared__ int sc[256][CLS];        // 9216 B, stride 9 -> conflict-benign
    const int t = threadIdx.x;
#pragma unroll
    for (int k = 0; k < CLS; ++k) sc[t][k] = hist[t * CLS + k];
    __syncthreads();
#pragma unroll
    for (int off = 128; off > 0; off >>= 1) {
        if (t < off) {
#pragma unroll
            for (int k = 0; k < CLS; ++k) sc[t][k] += sc[t + off][k];
        }
        __syncthreads();
    }

    // --- protos + broadcast ---
    const int idx = blockIdx.x * 256 + t;          // [0, CH*CLS)
    if (idx >= CH * CLS) return;
    const int k = idx % CLS;

    float acc = 0.0f;
#pragma unroll
    for (int np = 0; np < NB; ++np)                // coalesced: stride CH*CLS
        acc += partial[np * (CH * CLS) + idx];

    const float proto = acc / (float)max(sc[0][k], 1);
#pragma unroll
    for (int np = 0; np < NB; ++np)
        out[np * (CH * CLS) + idx] = proto;        // coalesced per round
}

// ---------------------------------------------------------------------------
extern "C" void kernel_launch(void* const* d_in, const int* in_sizes, int n_in,
                              void* d_out, int out_size, void* d_ws, size_t ws_size,
                              hipStream_t stream)
{
    const float* feat  = (const float*)d_in[0];
    const float* logit = (const float*)d_in[1];
    // d_in[2] is cls_num (== 9, fixed by the problem); hardcoded as CLS.

    // Workspace layout — every word fully overwritten before read, so the
    // harness's 0xAA poison needs no memset:
    //   [0,       147456)  float partial[SBLK][CLS]
    //   [147456,  156672)  int   hist[LBLK][CLS]
    //   [156928,  419072)  uint  labels4[PTOT/4]   (256 B-aligned start)
    char* ws = (char*)d_ws;
    float*        partial = (float*)ws;
    int*          hist    = (int*)(ws + 147456);
    unsigned int* labels4 = (unsigned int*)(ws + 156928);

    label_kernel<<<LBLK, 256, 0, stream>>>(logit, labels4, hist);
    sum_kernel<<<SBLK, 256, 0, stream>>>(feat, labels4, partial);
    finalize_kernel<<<(CH * CLS + 255) / 256, 256, 0, stream>>>(partial, hist, (float*)d_out);
}

// Round 3
// 352.940 us; speedup vs baseline: 1.0856x; 1.0605x over previous
//
#include <hip/hip_runtime.h>

// Problem constants (fixed by the reference setup_inputs):
// feat  [N=16, C=256, H=128, W=128] fp32
// logit [N=16, CLS=9, H=128, W=128] fp32
// out   [N, C, CLS] fp32 (broadcast of [C, CLS] protos)
#define HWN   16384            // H*W
#define NB    16               // batch
#define CH    256              // channels
#define CLS   9                // classes
#define PTOT  (NB * HWN)       // 262144 pixels
#define LBLK  (PTOT / 1024)    // 256 label blocks (4 px/thread, 256 thr)
#define SBLK  (NB * CH)        // 4096 sum blocks

typedef float v4f __attribute__((ext_vector_type(4)));

// ---------------------------------------------------------------------------
// K1: per-pixel argmax over CLS logits. 4 pixels/thread -> float4 logit loads
// (non-temporal: logit is read exactly once), packed uint label store.
// Per-block histogram to a distinct slot (no global atomics, no init needed).
// ---------------------------------------------------------------------------
__global__ __launch_bounds__(256) void label_kernel(
    const float* __restrict__ logit,
    unsigned int* __restrict__ labels4,   // [PTOT/4] packed 4 labels/uint
    int* __restrict__ hist)               // [LBLK][CLS]
{
    __shared__ int h[CLS];
    if (threadIdx.x < CLS) h[threadIdx.x] = 0;
    __syncthreads();

    const int t  = blockIdx.x * 256 + threadIdx.x;  // packed-uint index
    const int p0 = t << 2;                          // first pixel of the 4
    const int n  = p0 >> 14;                        // / HWN (same n for all 4)
    const int hw = p0 & (HWN - 1);
    const v4f* base = (const v4f*)(logit + (size_t)n * CLS * HWN + hw);

    v4f best = __builtin_nontemporal_load(base);
    int b0 = 0, b1 = 0, b2 = 0, b3 = 0;
#pragma unroll
    for (int k = 1; k < CLS; ++k) {
        const v4f v = __builtin_nontemporal_load(base + (size_t)k * (HWN / 4));
        if (v[0] > best[0]) { best[0] = v[0]; b0 = k; }  // strict > == jnp.argmax tie-break
        if (v[1] > best[1]) { best[1] = v[1]; b1 = k; }
        if (v[2] > best[2]) { best[2] = v[2]; b2 = k; }
        if (v[3] > best[3]) { best[3] = v[3]; b3 = k; }
    }
    labels4[t] = (unsigned)b0 | ((unsigned)b1 << 8) |
                 ((unsigned)b2 << 16) | ((unsigned)b3 << 24);

    atomicAdd(&h[b0], 1); atomicAdd(&h[b1], 1);
    atomicAdd(&h[b2], 1); atomicAdd(&h[b3], 1);
    __syncthreads();
    if (threadIdx.x < CLS) hist[blockIdx.x * CLS + threadIdx.x] = h[threadIdx.x];
}

// ---------------------------------------------------------------------------
// K2: one block per (n,c) slab of 16384 contiguous floats. Non-temporal
// float4 feat loads (feat is streamed exactly once -> don't pollute L2),
// cached uint label loads (256 KiB total, L2-resident across 4096 blocks).
// Register class-bins -> wave shuffle tree -> cross-wave LDS -> per-block
// partial written to a distinct slot (no atomics, no init).
// ---------------------------------------------------------------------------
__global__ __launch_bounds__(256) void sum_kernel(
    const float* __restrict__ feat,
    const unsigned int* __restrict__ labels4,
    float* __restrict__ partial)   // [SBLK][CLS]
{
    const int b = blockIdx.x;            // b = n*CH + c == feat slab index
    const int n = b >> 8;

    const v4f*          f4 = (const v4f*)(feat + (size_t)b * HWN);
    const unsigned int* l4 = labels4 + (size_t)n * (HWN / 4);

    float s[CLS];
#pragma unroll
    for (int k = 0; k < CLS; ++k) s[k] = 0.0f;

    // 4096 float4 chunks, 256 threads -> 16 iterations each; unroll 8 keeps
    // 8 dwordx4 loads in flight per thread.
#pragma unroll 8
    for (int i = threadIdx.x; i < HWN / 4; i += 256) {
        const v4f          v  = __builtin_nontemporal_load(&f4[i]);
        const unsigned int lu = l4[i];
#pragma unroll
        for (int j = 0; j < 4; ++j) {
            const float x = v[j];
            const int   l = (lu >> (8 * j)) & 255;
#pragma unroll
            for (int k = 0; k < CLS; ++k)
                s[k] += (l == k) ? x : 0.0f;
        }
    }

    // Wave(64) shuffle-tree reduction per class, then cross-wave via LDS.
#pragma unroll
    for (int k = 0; k < CLS; ++k)
        for (int off = 32; off > 0; off >>= 1)
            s[k] += __shfl_down(s[k], off, 64);

    __shared__ float wsum[4][CLS];
    const int wave = threadIdx.x >> 6;
    if ((threadIdx.x & 63) == 0) {
#pragma unroll
        for (int k = 0; k < CLS; ++k) wsum[wave][k] = s[k];
    }
    __syncthreads();

    if (threadIdx.x < CLS) {
        const int k = threadIdx.x;
        partial[b * CLS + k] = wsum[0][k] + wsum[1][k] + wsum[2][k] + wsum[3][k];
    }
}

// ---------------------------------------------------------------------------
// K3: reduce 16 n-partials per (c,k), divide by counts (reduced from hist),
// broadcast-write out[n][c][k]. 9 blocks x 256 threads = 2304 = CH*CLS.
// ---------------------------------------------------------------------------
__global__ __launch_bounds__(256) void finalize_kernel(
    const float* __restrict__ partial,  // [SBLK][CLS]
    const int* __restrict__ hist,       // [LBLK][CLS]
    float* __restrict__ out)            // [NB][CH][CLS]
{
    // --- counts: tree-reduce the 256 per-block histograms (redundant/block) ---
    __shared__ int sc[256][CLS];        // 9216 B, stride 9 -> conflict-benign
    const int t = threadIdx.x;
#pragma unroll
    for (int k = 0; k < CLS; ++k) sc[t][k] = hist[t * CLS + k];
    __syncthreads();
#pragma unroll
    for (int off = 128; off > 0; off >>= 1) {
        if (t < off) {
#pragma unroll
            for (int k = 0; k < CLS; ++k) sc[t][k] += sc[t + off][k];
        }
        __syncthreads();
    }

    // --- protos + broadcast ---
    const int idx = blockIdx.x * 256 + t;          // [0, CH*CLS)
    if (idx >= CH * CLS) return;
    const int k = idx % CLS;

    float acc = 0.0f;
#pragma unroll
    for (int np = 0; np < NB; ++np)                // coalesced: stride CH*CLS
        acc += partial[np * (CH * CLS) + idx];

    const float proto = acc / (float)max(sc[0][k], 1);
#pragma unroll
    for (int np = 0; np < NB; ++np)
        out[np * (CH * CLS) + idx] = proto;        // coalesced per round
}

// ---------------------------------------------------------------------------
extern "C" void kernel_launch(void* const* d_in, const int* in_sizes, int n_in,
                              void* d_out, int out_size, void* d_ws, size_t ws_size,
                              hipStream_t stream)
{
    const float* feat  = (const float*)d_in[0];
    const float* logit = (const float*)d_in[1];
    // d_in[2] is cls_num (== 9, fixed by the problem); hardcoded as CLS.

    // Workspace layout — every word fully overwritten before read, so the
    // harness's 0xAA poison needs no memset:
    //   [0,       147456)  float partial[SBLK][CLS]
    //   [147456,  156672)  int   hist[LBLK][CLS]
    //   [156928,  419072)  uint  labels4[PTOT/4]   (256 B-aligned start)
    char* ws = (char*)d_ws;
    float*        partial = (float*)ws;
    int*          hist    = (int*)(ws + 147456);
    unsigned int* labels4 = (unsigned int*)(ws + 156928);

    label_kernel<<<LBLK, 256, 0, stream>>>(logit, labels4, hist);
    sum_kernel<<<SBLK, 256, 0, stream>>>(feat, labels4, partial);
    finalize_kernel<<<(CH * CLS + 255) / 256, 256, 0, stream>>>(partial, hist, (float*)d_out);
}